// Round 4
// baseline (393.786 us; speedup 1.0000x reference)
//
#include <hip/hip_runtime.h>

typedef __bf16 bf16_t;
typedef __bf16 bf16x8 __attribute__((ext_vector_type(8)));
typedef float f32x4 __attribute__((ext_vector_type(4)));

#define MFMA(a, b, c) __builtin_amdgcn_mfma_f32_16x16x32_bf16((a), (b), (c), 0, 0, 0)

#define E_ROWS 640000
#define BM 128

static __device__ __forceinline__ bf16x8 cvt8(float4 a, float4 b) {
  bf16x8 r;
  r[0] = (bf16_t)a.x; r[1] = (bf16_t)a.y; r[2] = (bf16_t)a.z; r[3] = (bf16_t)a.w;
  r[4] = (bf16_t)b.x; r[5] = (bf16_t)b.y; r[6] = (bf16_t)b.z; r[7] = (bf16_t)b.w;
  return r;
}

static __device__ __forceinline__ unsigned int pk2(float a, float b) {
  unsigned short ua = __builtin_bit_cast(unsigned short, (bf16_t)a);
  unsigned short ub = __builtin_bit_cast(unsigned short, (bf16_t)b);
  return ((unsigned int)ub << 16) | ua;
}

// Fragment-ordered weights in ws (unchanged layout; data identical whether the
// fragment is used as MFMA A-operand (Wt rows = output features) or B-operand).
//   GEMM1 (Wm1): f =   0 + ks*8 + nb   (ks 0..7, nb 0..7)
//   GEMM2 (Wm2): f =  64 + ks*8 + nb   (ks 0..3)
//   GEMM3 (Wu1): f =  96 + ks*8 + nb   (ks 0..7)
//   GEMM4 (Wu2): f = 160 + ks*8 + nb   (ks 0..3)
// chunk c = f*64 + lane holds 8 bf16: W[k][n], k = 32*ks + 8*(lane>>4) + j,
// n = 16*nb + (lane&15).
__global__ __launch_bounds__(256) void prep_weights(
    const float* __restrict__ Wm1, const float* __restrict__ Wm2,
    const float* __restrict__ Wu1, const float* __restrict__ Wu2,
    bf16_t* __restrict__ wt) {
  int c = blockIdx.x * 256 + threadIdx.x;  // 12288 chunks of 16B
  if (c >= 12288) return;
  int lane = c & 63, f = c >> 6;
  const float* W; int base;
  if (f < 64)       { W = Wm1; base = 0;   }
  else if (f < 96)  { W = Wm2; base = 64;  }
  else if (f < 160) { W = Wu1; base = 96;  }
  else              { W = Wu2; base = 160; }
  int fl = f - base;
  int ks = fl >> 3, nb = fl & 7;
  int k0 = 32 * ks + 8 * (lane >> 4);
  int n  = 16 * nb + (lane & 15);
  bf16x8 v;
  #pragma unroll
  for (int j = 0; j < 8; ++j) v[j] = (bf16_t)W[(size_t)(k0 + j) * 128 + n];
  ((bf16x8*)wt)[c] = v;
}

static __device__ __forceinline__ void loadW(bf16x8* dst, const bf16x8* gb,
                                             int fragbase, int lane) {
  #pragma unroll
  for (int n = 0; n < 8; ++n) dst[n] = gb[(fragbase + n) * 64 + lane];
}

// Transposed-chain fused kernel: every GEMM computes h^T = W^T * x^T.
// MFMA A-operand = W-frag, B-operand = x-frag. D (C-layout) holds, for lane
// (c = lane&15, g = lane>>4): h[rowbase + 16*mt + c][feature 16*nb + 4*g + e].
// Repack to next GEMM's B-frag via per-wave LDS u64 scatter (no barriers).
//
// amdgpu_waves_per_eu(2,2): pin regalloc budget to 256 unified regs/wave.
// Without it the compiler targets 3 waves/SIMD (VGPR_Count=80 in R3) and
// spills the W/x fragments to scratch -> every MFMA group stalls on scratch
// fills -> 125kcyc wave lifetimes, MfmaUtil 13%. Live set ~210 regs fits 256.
__global__ __launch_bounds__(256)
__attribute__((amdgpu_waves_per_eu(2, 2))) void fused_mp(
    const float* __restrict__ hself, const float* __restrict__ hother,
    const bf16_t* __restrict__ wt,
    const float* __restrict__ bm1, const float* __restrict__ bm2,
    const float* __restrict__ bu1, const float* __restrict__ bu2,
    float* __restrict__ out) {
  // per-wave repack region: [mt(2)][ks(4)][lane(64)] * 16B = 8 KB; 4 waves = 32 KB
  __shared__ bf16_t repack[4 * 4096];

  const int tid = threadIdx.x;
  const int lane = tid & 63;
  const int wave = tid >> 6;
  const int c = lane & 15;
  const int g = lane >> 4;

  char* myrep = (char*)(repack + wave * 4096);
  const bf16x8* gb = (const bf16x8*)wt;
  const size_t rowbase = (size_t)blockIdx.x * BM + wave * 32;

  // ---- load x fragments (B-operand layout == old A layout), f32 -> bf16 ----
  bf16x8 hsf[2][4], hof[2][4];
  {
    float4 t0[2][4], t1[2][4], u0[2][4], u1[2][4];
    #pragma unroll
    for (int mt = 0; mt < 2; ++mt) {
      #pragma unroll
      for (int ks = 0; ks < 4; ++ks) {
        size_t row = rowbase + mt * 16 + c;
        const float* p = hself + row * 128 + ks * 32 + g * 8;
        t0[mt][ks] = *(const float4*)p;
        t1[mt][ks] = *(const float4*)(p + 4);
        const float* q = hother + row * 128 + ks * 32 + g * 8;
        u0[mt][ks] = *(const float4*)q;
        u1[mt][ks] = *(const float4*)(q + 4);
      }
    }
    #pragma unroll
    for (int mt = 0; mt < 2; ++mt) {
      #pragma unroll
      for (int ks = 0; ks < 4; ++ks) {
        hsf[mt][ks] = cvt8(t0[mt][ks], t1[mt][ks]);
        hof[mt][ks] = cvt8(u0[mt][ks], u1[mt][ks]);
      }
    }
  }

  f32x4 acc[2][8];
  bf16x8 wA[8], wB[8];

  // ============ GEMM1: h1^T = Wm1^T [hs|ho]^T  (+bm1 via acc init, relu) ====
  #pragma unroll
  for (int nb = 0; nb < 8; ++nb) {
    float4 b4 = *(const float4*)(bm1 + nb * 16 + g * 4);
    acc[0][nb] = (f32x4){b4.x, b4.y, b4.z, b4.w};
    acc[1][nb] = acc[0][nb];
  }
  loadW(wA, gb, 0, lane);
  #pragma unroll
  for (int ks = 0; ks < 8; ++ks) {
    bf16x8* wc = (ks & 1) ? wB : wA;
    bf16x8* wn = (ks & 1) ? wA : wB;
    if (ks < 7) loadW(wn, gb, (ks + 1) * 8, lane);
    bf16x8 x0 = (ks < 4) ? hsf[0][ks & 3] : hof[0][ks & 3];
    bf16x8 x1 = (ks < 4) ? hsf[1][ks & 3] : hof[1][ks & 3];
    #pragma unroll
    for (int nb = 0; nb < 8; ++nb) {
      acc[0][nb] = MFMA(wc[nb], x0, acc[0][nb]);
      acc[1][nb] = MFMA(wc[nb], x1, acc[1][nb]);
    }
  }

  // repack epilogue 1: relu, pack to bf16 pairs, u64 scatter to B-frag layout
  #pragma unroll
  for (int mt = 0; mt < 2; ++mt)
    #pragma unroll
    for (int nb = 0; nb < 8; ++nb) {
      f32x4 v = acc[mt][nb];
      uint2 w;
      w.x = pk2(fmaxf(v[0], 0.f), fmaxf(v[1], 0.f));
      w.y = pk2(fmaxf(v[2], 0.f), fmaxf(v[3], 0.f));
      int dstlane = c + 16 * (2 * (nb & 1) + (g >> 1));
      int off = ((mt * 4 + (nb >> 1)) * 64 + dstlane) * 16 + (g & 1) * 8;
      *(uint2*)(myrep + off) = w;
    }
  asm volatile("s_waitcnt lgkmcnt(0)" ::: "memory");
  bf16x8 h1B[2][4];
  #pragma unroll
  for (int mt = 0; mt < 2; ++mt)
    #pragma unroll
    for (int ks = 0; ks < 4; ++ks)
      h1B[mt][ks] = *(const bf16x8*)(myrep + ((mt * 4 + ks) * 64 + lane) * 16);

  // ============ GEMM2: msg^T = Wm2^T h1^T  (+bm2, no relu) =================
  #pragma unroll
  for (int nb = 0; nb < 8; ++nb) {
    float4 b4 = *(const float4*)(bm2 + nb * 16 + g * 4);
    acc[0][nb] = (f32x4){b4.x, b4.y, b4.z, b4.w};
    acc[1][nb] = acc[0][nb];
  }
  loadW(wA, gb, 64, lane);
  #pragma unroll
  for (int ks = 0; ks < 4; ++ks) {
    bf16x8* wc = (ks & 1) ? wB : wA;
    bf16x8* wn = (ks & 1) ? wA : wB;
    if (ks < 3) loadW(wn, gb, 64 + (ks + 1) * 8, lane);
    #pragma unroll
    for (int nb = 0; nb < 8; ++nb) {
      acc[0][nb] = MFMA(wc[nb], h1B[0][ks], acc[0][nb]);
      acc[1][nb] = MFMA(wc[nb], h1B[1][ks], acc[1][nb]);
    }
  }

  // repack epilogue 2 (no relu) -> msg B-frags
  #pragma unroll
  for (int mt = 0; mt < 2; ++mt)
    #pragma unroll
    for (int nb = 0; nb < 8; ++nb) {
      f32x4 v = acc[mt][nb];
      uint2 w;
      w.x = pk2(v[0], v[1]);
      w.y = pk2(v[2], v[3]);
      int dstlane = c + 16 * (2 * (nb & 1) + (g >> 1));
      int off = ((mt * 4 + (nb >> 1)) * 64 + dstlane) * 16 + (g & 1) * 8;
      *(uint2*)(myrep + off) = w;
    }
  asm volatile("s_waitcnt lgkmcnt(0)" ::: "memory");
  bf16x8 msgB[2][4];
  #pragma unroll
  for (int mt = 0; mt < 2; ++mt)
    #pragma unroll
    for (int ks = 0; ks < 4; ++ks)
      msgB[mt][ks] = *(const bf16x8*)(myrep + ((mt * 4 + ks) * 64 + lane) * 16);

  // ============ GEMM3: h2^T = Wu1^T [hs|msg]^T  (+bu1, relu) ===============
  #pragma unroll
  for (int nb = 0; nb < 8; ++nb) {
    float4 b4 = *(const float4*)(bu1 + nb * 16 + g * 4);
    acc[0][nb] = (f32x4){b4.x, b4.y, b4.z, b4.w};
    acc[1][nb] = acc[0][nb];
  }
  loadW(wA, gb, 96, lane);
  #pragma unroll
  for (int ks = 0; ks < 8; ++ks) {
    bf16x8* wc = (ks & 1) ? wB : wA;
    bf16x8* wn = (ks & 1) ? wA : wB;
    if (ks < 7) loadW(wn, gb, 96 + (ks + 1) * 8, lane);
    bf16x8 x0 = (ks < 4) ? hsf[0][ks & 3] : msgB[0][ks & 3];
    bf16x8 x1 = (ks < 4) ? hsf[1][ks & 3] : msgB[1][ks & 3];
    #pragma unroll
    for (int nb = 0; nb < 8; ++nb) {
      acc[0][nb] = MFMA(wc[nb], x0, acc[0][nb]);
      acc[1][nb] = MFMA(wc[nb], x1, acc[1][nb]);
    }
  }

  // repack epilogue 3: relu -> h2 B-frags
  #pragma unroll
  for (int mt = 0; mt < 2; ++mt)
    #pragma unroll
    for (int nb = 0; nb < 8; ++nb) {
      f32x4 v = acc[mt][nb];
      uint2 w;
      w.x = pk2(fmaxf(v[0], 0.f), fmaxf(v[1], 0.f));
      w.y = pk2(fmaxf(v[2], 0.f), fmaxf(v[3], 0.f));
      int dstlane = c + 16 * (2 * (nb & 1) + (g >> 1));
      int off = ((mt * 4 + (nb >> 1)) * 64 + dstlane) * 16 + (g & 1) * 8;
      *(uint2*)(myrep + off) = w;
    }
  asm volatile("s_waitcnt lgkmcnt(0)" ::: "memory");
  bf16x8 h2B[2][4];
  #pragma unroll
  for (int mt = 0; mt < 2; ++mt)
    #pragma unroll
    for (int ks = 0; ks < 4; ++ks)
      h2B[mt][ks] = *(const bf16x8*)(myrep + ((mt * 4 + ks) * 64 + lane) * 16);

  // ============ GEMM4: out^T = Wu2^T h2^T  (+bu2) ==========================
  #pragma unroll
  for (int nb = 0; nb < 8; ++nb) {
    float4 b4 = *(const float4*)(bu2 + nb * 16 + g * 4);
    acc[0][nb] = (f32x4){b4.x, b4.y, b4.z, b4.w};
    acc[1][nb] = acc[0][nb];
  }
  loadW(wA, gb, 160, lane);
  #pragma unroll
  for (int ks = 0; ks < 4; ++ks) {
    bf16x8* wc = (ks & 1) ? wB : wA;
    bf16x8* wn = (ks & 1) ? wA : wB;
    if (ks < 3) loadW(wn, gb, 160 + (ks + 1) * 8, lane);
    #pragma unroll
    for (int nb = 0; nb < 8; ++nb) {
      acc[0][nb] = MFMA(wc[nb], h2B[0][ks], acc[0][nb]);
      acc[1][nb] = MFMA(wc[nb], h2B[1][ks], acc[1][nb]);
    }
  }

  // final store: per (mt,nb) a float4 at out[row][16nb+4g]; 16x64B segments/instr
  #pragma unroll
  for (int mt = 0; mt < 2; ++mt)
    #pragma unroll
    for (int nb = 0; nb < 8; ++nb) {
      size_t row = rowbase + mt * 16 + c;
      f32x4 v = acc[mt][nb];
      *(float4*)(out + row * 128 + nb * 16 + g * 4) =
          (float4){v[0], v[1], v[2], v[3]};
    }
}

extern "C" void kernel_launch(void* const* d_in, const int* in_sizes, int n_in,
                              void* d_out, int out_size, void* d_ws, size_t ws_size,
                              hipStream_t stream) {
  const float* hself  = (const float*)d_in[0];
  const float* hother = (const float*)d_in[1];
  const float* Wm1 = (const float*)d_in[2];
  const float* bm1 = (const float*)d_in[3];
  const float* Wm2 = (const float*)d_in[4];
  const float* bm2 = (const float*)d_in[5];
  const float* Wu1 = (const float*)d_in[6];
  const float* bu1 = (const float*)d_in[7];
  const float* Wu2 = (const float*)d_in[8];
  const float* bu2 = (const float*)d_in[9];
  float* out = (float*)d_out;
  bf16_t* wt = (bf16_t*)d_ws;  // 196608 B of fragment-ordered bf16 weights

  prep_weights<<<48, 256, 0, stream>>>(Wm1, Wm2, Wu1, Wu2, wt);
  fused_mp<<<E_ROWS / BM, 256, 0, stream>>>(hself, hother, wt,
                                            bm1, bm2, bu1, bu2, out);
}

// Round 6
// 388.925 us; speedup vs baseline: 1.0125x; 1.0125x over previous
//
#include <hip/hip_runtime.h>

typedef __bf16 bf16_t;
typedef __bf16 bf16x8 __attribute__((ext_vector_type(8)));
typedef float f32x4 __attribute__((ext_vector_type(4)));

#define MFMA(a, b, c) __builtin_amdgcn_mfma_f32_16x16x32_bf16((a), (b), (c), 0, 0, 0)

#define E_ROWS 640000
#define BM 128

static __device__ __forceinline__ bf16x8 cvt8(float4 a, float4 b) {
  bf16x8 r;
  r[0] = (bf16_t)a.x; r[1] = (bf16_t)a.y; r[2] = (bf16_t)a.z; r[3] = (bf16_t)a.w;
  r[4] = (bf16_t)b.x; r[5] = (bf16_t)b.y; r[6] = (bf16_t)b.z; r[7] = (bf16_t)b.w;
  return r;
}

static __device__ __forceinline__ unsigned int pk2(float a, float b) {
  unsigned short ua = __builtin_bit_cast(unsigned short, (bf16_t)a);
  unsigned short ub = __builtin_bit_cast(unsigned short, (bf16_t)b);
  return ((unsigned int)ub << 16) | ua;
}

// Fragment-ordered weights in ws:
//   GEMM1 (Wm1): f =   0 + ks*8 + nb   (ks 0..7, nb 0..7)
//   GEMM2 (Wm2): f =  64 + ks*8 + nb   (ks 0..3)
//   GEMM3 (Wu1): f =  96 + ks*8 + nb   (ks 0..7)
//   GEMM4 (Wu2): f = 160 + ks*8 + nb   (ks 0..3)
// chunk c = f*64 + lane holds 8 bf16: W[k][n], k = 32*ks + 8*(lane>>4) + j,
// n = 16*nb + (lane&15).
__global__ __launch_bounds__(256) void prep_weights(
    const float* __restrict__ Wm1, const float* __restrict__ Wm2,
    const float* __restrict__ Wu1, const float* __restrict__ Wu2,
    bf16_t* __restrict__ wt) {
  int c = blockIdx.x * 256 + threadIdx.x;  // 12288 chunks of 16B
  if (c >= 12288) return;
  int lane = c & 63, f = c >> 6;
  const float* W; int base;
  if (f < 64)       { W = Wm1; base = 0;   }
  else if (f < 96)  { W = Wm2; base = 64;  }
  else if (f < 160) { W = Wu1; base = 96;  }
  else              { W = Wu2; base = 160; }
  int fl = f - base;
  int ks = fl >> 3, nb = fl & 7;
  int k0 = 32 * ks + 8 * (lane >> 4);
  int n  = 16 * nb + (lane & 15);
  bf16x8 v;
  #pragma unroll
  for (int j = 0; j < 8; ++j) v[j] = (bf16_t)W[(size_t)(k0 + j) * 128 + n];
  ((bf16x8*)wt)[c] = v;
}

// ---------------- macro-expanded, alloca-free fused kernel ----------------
// Rule #20 fix: ALL fragments are named scalars; every index below is a
// compile-time literal; no pointer selects. In R2-R4 the (ks&1)?wB:wA and
// (ks<4)?hsf:hof selects kept the fragment arrays as allocas -> scratch
// (L2-backed, invisible in FETCH_SIZE) -> every MFMA operand read at ~200cyc
// -> 100kcyc wave lifetimes, MfmaUtil 12%, VGPR_Count 80-88.

#define LOADW8(s, fb) \
  s##0 = gb[(fb + 0) * 64 + lane]; \
  s##1 = gb[(fb + 1) * 64 + lane]; \
  s##2 = gb[(fb + 2) * 64 + lane]; \
  s##3 = gb[(fb + 3) * 64 + lane]; \
  s##4 = gb[(fb + 4) * 64 + lane]; \
  s##5 = gb[(fb + 5) * 64 + lane]; \
  s##6 = gb[(fb + 6) * 64 + lane]; \
  s##7 = gb[(fb + 7) * 64 + lane];

#define ROUND(s, x0, x1) \
  acc00 = MFMA(s##0, x0, acc00); acc10 = MFMA(s##0, x1, acc10); \
  acc01 = MFMA(s##1, x0, acc01); acc11 = MFMA(s##1, x1, acc11); \
  acc02 = MFMA(s##2, x0, acc02); acc12 = MFMA(s##2, x1, acc12); \
  acc03 = MFMA(s##3, x0, acc03); acc13 = MFMA(s##3, x1, acc13); \
  acc04 = MFMA(s##4, x0, acc04); acc14 = MFMA(s##4, x1, acc14); \
  acc05 = MFMA(s##5, x0, acc05); acc15 = MFMA(s##5, x1, acc15); \
  acc06 = MFMA(s##6, x0, acc06); acc16 = MFMA(s##6, x1, acc16); \
  acc07 = MFMA(s##7, x0, acc07); acc17 = MFMA(s##7, x1, acc17);

#define ACCINIT(bp) { float4 q; \
  q = *(const float4*)((bp) +   0 + g * 4); acc00 = (f32x4){q.x,q.y,q.z,q.w}; acc10 = acc00; \
  q = *(const float4*)((bp) +  16 + g * 4); acc01 = (f32x4){q.x,q.y,q.z,q.w}; acc11 = acc01; \
  q = *(const float4*)((bp) +  32 + g * 4); acc02 = (f32x4){q.x,q.y,q.z,q.w}; acc12 = acc02; \
  q = *(const float4*)((bp) +  48 + g * 4); acc03 = (f32x4){q.x,q.y,q.z,q.w}; acc13 = acc03; \
  q = *(const float4*)((bp) +  64 + g * 4); acc04 = (f32x4){q.x,q.y,q.z,q.w}; acc14 = acc04; \
  q = *(const float4*)((bp) +  80 + g * 4); acc05 = (f32x4){q.x,q.y,q.z,q.w}; acc15 = acc05; \
  q = *(const float4*)((bp) +  96 + g * 4); acc06 = (f32x4){q.x,q.y,q.z,q.w}; acc16 = acc06; \
  q = *(const float4*)((bp) + 112 + g * 4); acc07 = (f32x4){q.x,q.y,q.z,q.w}; acc17 = acc07; }

// repack one acc tile: D holds h[rowbase+16*mt+c][16*nb+4*g+e]; scatter so a
// later 16B read at ((mt*4+ks)*64+lane)*16 yields the B-frag for GEMM k-step.
#define RPK(av, mt, nb, R) { \
  f32x4 v = av; \
  float e0 = v[0], e1 = v[1], e2 = v[2], e3 = v[3]; \
  if (R) { e0 = fmaxf(e0, 0.f); e1 = fmaxf(e1, 0.f); \
           e2 = fmaxf(e2, 0.f); e3 = fmaxf(e3, 0.f); } \
  uint2 w; w.x = pk2(e0, e1); w.y = pk2(e2, e3); \
  int dl = c + 16 * (2 * ((nb) & 1) + (g >> 1)); \
  *(uint2*)(myrep + (((mt) * 4 + ((nb) >> 1)) * 64 + dl) * 16 + (g & 1) * 8) = w; }

#define RPK_ALL(R) \
  RPK(acc00, 0, 0, R) RPK(acc01, 0, 1, R) RPK(acc02, 0, 2, R) RPK(acc03, 0, 3, R) \
  RPK(acc04, 0, 4, R) RPK(acc05, 0, 5, R) RPK(acc06, 0, 6, R) RPK(acc07, 0, 7, R) \
  RPK(acc10, 1, 0, R) RPK(acc11, 1, 1, R) RPK(acc12, 1, 2, R) RPK(acc13, 1, 3, R) \
  RPK(acc14, 1, 4, R) RPK(acc15, 1, 5, R) RPK(acc16, 1, 6, R) RPK(acc17, 1, 7, R)

#define WAITLDS asm volatile("s_waitcnt lgkmcnt(0)" ::: "memory");

#define RDB(d00, d01, d02, d03, d10, d11, d12, d13) \
  d00 = *(const bf16x8*)(myrep + (0 * 64 + lane) * 16); \
  d01 = *(const bf16x8*)(myrep + (1 * 64 + lane) * 16); \
  d02 = *(const bf16x8*)(myrep + (2 * 64 + lane) * 16); \
  d03 = *(const bf16x8*)(myrep + (3 * 64 + lane) * 16); \
  d10 = *(const bf16x8*)(myrep + (4 * 64 + lane) * 16); \
  d11 = *(const bf16x8*)(myrep + (5 * 64 + lane) * 16); \
  d12 = *(const bf16x8*)(myrep + (6 * 64 + lane) * 16); \
  d13 = *(const bf16x8*)(myrep + (7 * 64 + lane) * 16);

#define LOADX(d0, d1, basep, kk) { \
  float4 a0 = *(const float4*)((basep) + r0 + (kk) * 32); \
  float4 a1 = *(const float4*)((basep) + r0 + (kk) * 32 + 4); \
  float4 b0 = *(const float4*)((basep) + r1 + (kk) * 32); \
  float4 b1 = *(const float4*)((basep) + r1 + (kk) * 32 + 4); \
  d0 = cvt8(a0, a1); d1 = cvt8(b0, b1); }

#define ST(av, mt, nb) { f32x4 v = av; \
  *(float4*)(out + (rowbase + (mt) * 16 + c) * 128 + (nb) * 16 + g * 4) = \
      (float4){v[0], v[1], v[2], v[3]}; }

__global__ __launch_bounds__(256)
__attribute__((amdgpu_waves_per_eu(2, 2))) void fused_mp(
    const float* __restrict__ hself, const float* __restrict__ hother,
    const bf16_t* __restrict__ wt,
    const float* __restrict__ bm1, const float* __restrict__ bm2,
    const float* __restrict__ bu1, const float* __restrict__ bu2,
    float* __restrict__ out) {
  // per-wave repack region: 8KB; 4 waves = 32 KB
  __shared__ bf16_t repack[4 * 4096];

  const int tid = threadIdx.x;
  const int lane = tid & 63;
  const int wave = tid >> 6;
  const int c = lane & 15;
  const int g = lane >> 4;

  char* myrep = (char*)(repack + wave * 4096);
  const bf16x8* gb = (const bf16x8*)wt;
  const size_t rowbase = (size_t)blockIdx.x * BM + wave * 32;
  const size_t r0 = (rowbase + c) * 128 + g * 8;       // float offsets, mt=0
  const size_t r1 = (rowbase + 16 + c) * 128 + g * 8;  // mt=1

  // ---- x fragments (named), f32 -> bf16 ----
  bf16x8 hs00, hs01, hs02, hs03, hs10, hs11, hs12, hs13;
  bf16x8 ho00, ho01, ho02, ho03, ho10, ho11, ho12, ho13;
  LOADX(hs00, hs10, hself, 0)
  LOADX(hs01, hs11, hself, 1)
  LOADX(hs02, hs12, hself, 2)
  LOADX(hs03, hs13, hself, 3)
  LOADX(ho00, ho10, hother, 0)
  LOADX(ho01, ho11, hother, 1)
  LOADX(ho02, ho12, hother, 2)
  LOADX(ho03, ho13, hother, 3)

  f32x4 acc00, acc01, acc02, acc03, acc04, acc05, acc06, acc07;
  f32x4 acc10, acc11, acc12, acc13, acc14, acc15, acc16, acc17;
  bf16x8 wa0, wa1, wa2, wa3, wa4, wa5, wa6, wa7;
  bf16x8 wb0, wb1, wb2, wb3, wb4, wb5, wb6, wb7;

  // ============ GEMM1: h1^T = Wm1^T [hs|ho]^T  (+bm1, relu) ============
  ACCINIT(bm1)
  LOADW8(wa, 0)
  LOADW8(wb, 8)   ROUND(wa, hs00, hs10)
  LOADW8(wa, 16)  ROUND(wb, hs01, hs11)
  LOADW8(wb, 24)  ROUND(wa, hs02, hs12)
  LOADW8(wa, 32)  ROUND(wb, hs03, hs13)
  LOADW8(wb, 40)  ROUND(wa, ho00, ho10)
  LOADW8(wa, 48)  ROUND(wb, ho01, ho11)
  LOADW8(wb, 56)  ROUND(wa, ho02, ho12)
                  ROUND(wb, ho03, ho13)

  // repack -> h1 B-frags (t*)
  RPK_ALL(true)
  WAITLDS
  bf16x8 t00, t01, t02, t03, t10, t11, t12, t13;
  RDB(t00, t01, t02, t03, t10, t11, t12, t13)

  // ============ GEMM2: msg^T = Wm2^T h1^T  (+bm2, no relu) ============
  ACCINIT(bm2)
  LOADW8(wa, 64)
  LOADW8(wb, 72)  ROUND(wa, t00, t10)
  LOADW8(wa, 80)  ROUND(wb, t01, t11)
  LOADW8(wb, 88)  ROUND(wa, t02, t12)
                  ROUND(wb, t03, t13)

  // repack -> msg B-frags (m*)
  RPK_ALL(false)
  WAITLDS
  bf16x8 m00, m01, m02, m03, m10, m11, m12, m13;
  RDB(m00, m01, m02, m03, m10, m11, m12, m13)

  // ============ GEMM3: h2^T = Wu1^T [hs|msg]^T  (+bu1, relu) ============
  ACCINIT(bu1)
  LOADW8(wa, 96)
  LOADW8(wb, 104) ROUND(wa, hs00, hs10)
  LOADW8(wa, 112) ROUND(wb, hs01, hs11)
  LOADW8(wb, 120) ROUND(wa, hs02, hs12)
  LOADW8(wa, 128) ROUND(wb, hs03, hs13)
  LOADW8(wb, 136) ROUND(wa, m00, m10)
  LOADW8(wa, 144) ROUND(wb, m01, m11)
  LOADW8(wb, 152) ROUND(wa, m02, m12)
                  ROUND(wb, m03, m13)

  // repack -> h2 B-frags (reuse t*)
  RPK_ALL(true)
  WAITLDS
  RDB(t00, t01, t02, t03, t10, t11, t12, t13)

  // ============ GEMM4: out^T = Wu2^T h2^T  (+bu2) ============
  ACCINIT(bu2)
  LOADW8(wa, 160)
  LOADW8(wb, 168) ROUND(wa, t00, t10)
  LOADW8(wa, 176) ROUND(wb, t01, t11)
  LOADW8(wb, 184) ROUND(wa, t02, t12)
                  ROUND(wb, t03, t13)

  // final store: 16 float4 stores, 64B segments per quarter-wave
  ST(acc00, 0, 0) ST(acc01, 0, 1) ST(acc02, 0, 2) ST(acc03, 0, 3)
  ST(acc04, 0, 4) ST(acc05, 0, 5) ST(acc06, 0, 6) ST(acc07, 0, 7)
  ST(acc10, 1, 0) ST(acc11, 1, 1) ST(acc12, 1, 2) ST(acc13, 1, 3)
  ST(acc14, 1, 4) ST(acc15, 1, 5) ST(acc16, 1, 6) ST(acc17, 1, 7)
}

extern "C" void kernel_launch(void* const* d_in, const int* in_sizes, int n_in,
                              void* d_out, int out_size, void* d_ws, size_t ws_size,
                              hipStream_t stream) {
  const float* hself  = (const float*)d_in[0];
  const float* hother = (const float*)d_in[1];
  const float* Wm1 = (const float*)d_in[2];
  const float* bm1 = (const float*)d_in[3];
  const float* Wm2 = (const float*)d_in[4];
  const float* bm2 = (const float*)d_in[5];
  const float* Wu1 = (const float*)d_in[6];
  const float* bu1 = (const float*)d_in[7];
  const float* Wu2 = (const float*)d_in[8];
  const float* bu2 = (const float*)d_in[9];
  float* out = (float*)d_out;
  bf16_t* wt = (bf16_t*)d_ws;  // 196608 B of fragment-ordered bf16 weights

  prep_weights<<<48, 256, 0, stream>>>(Wm1, Wm2, Wu1, Wu2, wt);
  fused_mp<<<E_ROWS / BM, 256, 0, stream>>>(hself, hother, wt,
                                            bm1, bm2, bu1, bu2, out);
}

// Round 7
// 355.185 us; speedup vs baseline: 1.1087x; 1.0950x over previous
//
#include <hip/hip_runtime.h>

typedef __bf16 bf16_t;
typedef __bf16 bf16x8 __attribute__((ext_vector_type(8)));
typedef float f32x4 __attribute__((ext_vector_type(4)));

#define MFMA(a, b, c) __builtin_amdgcn_mfma_f32_16x16x32_bf16((a), (b), (c), 0, 0, 0)

#define E_ROWS 640000
#define BM 128

static __device__ __forceinline__ bf16x8 cvt8(float4 a, float4 b) {
  bf16x8 r;
  r[0] = (bf16_t)a.x; r[1] = (bf16_t)a.y; r[2] = (bf16_t)a.z; r[3] = (bf16_t)a.w;
  r[4] = (bf16_t)b.x; r[5] = (bf16_t)b.y; r[6] = (bf16_t)b.z; r[7] = (bf16_t)b.w;
  return r;
}

static __device__ __forceinline__ unsigned int pk2(float a, float b) {
  unsigned short ua = __builtin_bit_cast(unsigned short, (bf16_t)a);
  unsigned short ub = __builtin_bit_cast(unsigned short, (bf16_t)b);
  return ((unsigned int)ub << 16) | ua;
}

// async 16B global -> LDS DMA (dest = wave-uniform base + lane*16, no VGPR round-trip)
static __device__ __forceinline__ void gload_lds16(const void* g, void* l) {
  __builtin_amdgcn_global_load_lds(
      (const __attribute__((address_space(1))) unsigned int*)g,
      (__attribute__((address_space(3))) unsigned int*)l, 16, 0, 0);
}

// Fragment-ordered weights in ws (table chunk = frag*64 + lane, 16B each):
//   Wm1: frags 0..63 (chunks 0..4095)      Wm2: frags 64..95  (4096..6143)
//   Wu1: frags 96..159 (6144..10239)       Wu2: frags 160..191 (10240..12287)
// chunk holds 8 bf16: W[k][n], k = 32*ks + 8*(lane>>4) + j, n = 16*nb + (lane&15).
__global__ __launch_bounds__(256) void prep_weights(
    const float* __restrict__ Wm1, const float* __restrict__ Wm2,
    const float* __restrict__ Wu1, const float* __restrict__ Wu2,
    bf16_t* __restrict__ wt) {
  int c = blockIdx.x * 256 + threadIdx.x;  // 12288 chunks of 16B
  if (c >= 12288) return;
  int lane = c & 63, f = c >> 6;
  const float* W; int base;
  if (f < 64)       { W = Wm1; base = 0;   }
  else if (f < 96)  { W = Wm2; base = 64;  }
  else if (f < 160) { W = Wu1; base = 96;  }
  else              { W = Wu2; base = 160; }
  int fl = f - base;
  int ks = fl >> 3, nb = fl & 7;
  int k0 = 32 * ks + 8 * (lane >> 4);
  int n  = 16 * nb + (lane & 15);
  bf16x8 v;
  #pragma unroll
  for (int j = 0; j < 8; ++j) v[j] = (bf16_t)W[(size_t)(k0 + j) * 128 + n];
  ((bf16x8*)wt)[c] = v;
}

// stage 32KB (32 frags = 2048 chunks) from table chunk base tc0 into LDS region
#define STAGE32(dstBase, tc0) { \
  _Pragma("unroll") \
  for (int i_ = 0; i_ < 8; ++i_) \
    gload_lds16((const char*)wt + ((size_t)((tc0) + i_ * 256 + wave * 64 + lane)) * 16, \
                (dstBase) + (i_ * 256 + wave * 64) * 16); }

// 8 W-frags (one ks) from LDS region: per-lane 16B ds_read_b128, conflict-free
#define LDW8(s, base, fl0) \
  s##0 = *(const bf16x8*)((base) + ((fl0) + 0) * 1024 + lane * 16); \
  s##1 = *(const bf16x8*)((base) + ((fl0) + 1) * 1024 + lane * 16); \
  s##2 = *(const bf16x8*)((base) + ((fl0) + 2) * 1024 + lane * 16); \
  s##3 = *(const bf16x8*)((base) + ((fl0) + 3) * 1024 + lane * 16); \
  s##4 = *(const bf16x8*)((base) + ((fl0) + 4) * 1024 + lane * 16); \
  s##5 = *(const bf16x8*)((base) + ((fl0) + 5) * 1024 + lane * 16); \
  s##6 = *(const bf16x8*)((base) + ((fl0) + 6) * 1024 + lane * 16); \
  s##7 = *(const bf16x8*)((base) + ((fl0) + 7) * 1024 + lane * 16);

#define ROUND(s, x0, x1) \
  acc00 = MFMA(s##0, x0, acc00); acc10 = MFMA(s##0, x1, acc10); \
  acc01 = MFMA(s##1, x0, acc01); acc11 = MFMA(s##1, x1, acc11); \
  acc02 = MFMA(s##2, x0, acc02); acc12 = MFMA(s##2, x1, acc12); \
  acc03 = MFMA(s##3, x0, acc03); acc13 = MFMA(s##3, x1, acc13); \
  acc04 = MFMA(s##4, x0, acc04); acc14 = MFMA(s##4, x1, acc14); \
  acc05 = MFMA(s##5, x0, acc05); acc15 = MFMA(s##5, x1, acc15); \
  acc06 = MFMA(s##6, x0, acc06); acc16 = MFMA(s##6, x1, acc16); \
  acc07 = MFMA(s##7, x0, acc07); acc17 = MFMA(s##7, x1, acc17);

// biases from LDS (broadcast reads: same addr per g-group)
#define ACCINIT_L(goff) { const char* bp_ = BIAS + (goff) + g * 16; float4 q; \
  q = *(const float4*)(bp_ +   0); acc00 = (f32x4){q.x,q.y,q.z,q.w}; acc10 = acc00; \
  q = *(const float4*)(bp_ +  64); acc01 = (f32x4){q.x,q.y,q.z,q.w}; acc11 = acc01; \
  q = *(const float4*)(bp_ + 128); acc02 = (f32x4){q.x,q.y,q.z,q.w}; acc12 = acc02; \
  q = *(const float4*)(bp_ + 192); acc03 = (f32x4){q.x,q.y,q.z,q.w}; acc13 = acc03; \
  q = *(const float4*)(bp_ + 256); acc04 = (f32x4){q.x,q.y,q.z,q.w}; acc14 = acc04; \
  q = *(const float4*)(bp_ + 320); acc05 = (f32x4){q.x,q.y,q.z,q.w}; acc15 = acc05; \
  q = *(const float4*)(bp_ + 384); acc06 = (f32x4){q.x,q.y,q.z,q.w}; acc16 = acc06; \
  q = *(const float4*)(bp_ + 448); acc07 = (f32x4){q.x,q.y,q.z,q.w}; acc17 = acc07; }

// repack: D holds h[rowbase+16*mt+c][16*nb+4*g+e]; scatter so a later 16B read
// at ((mt*4+ks)*64+lane)*16 yields the next GEMM's B-frag.
#define RPK(av, mt, nb, R) { \
  f32x4 v = av; \
  float e0 = v[0], e1 = v[1], e2 = v[2], e3 = v[3]; \
  if (R) { e0 = fmaxf(e0, 0.f); e1 = fmaxf(e1, 0.f); \
           e2 = fmaxf(e2, 0.f); e3 = fmaxf(e3, 0.f); } \
  uint2 w; w.x = pk2(e0, e1); w.y = pk2(e2, e3); \
  int dl = c + 16 * (2 * ((nb) & 1) + (g >> 1)); \
  *(uint2*)(myrep + (((mt) * 4 + ((nb) >> 1)) * 64 + dl) * 16 + (g & 1) * 8) = w; }

#define RPK_ALL(R) \
  RPK(acc00, 0, 0, R) RPK(acc01, 0, 1, R) RPK(acc02, 0, 2, R) RPK(acc03, 0, 3, R) \
  RPK(acc04, 0, 4, R) RPK(acc05, 0, 5, R) RPK(acc06, 0, 6, R) RPK(acc07, 0, 7, R) \
  RPK(acc10, 1, 0, R) RPK(acc11, 1, 1, R) RPK(acc12, 1, 2, R) RPK(acc13, 1, 3, R) \
  RPK(acc14, 1, 4, R) RPK(acc15, 1, 5, R) RPK(acc16, 1, 6, R) RPK(acc17, 1, 7, R)

#define WAITLDS asm volatile("s_waitcnt lgkmcnt(0)" ::: "memory");
#define VMCNT0  asm volatile("s_waitcnt vmcnt(0)" ::: "memory");
#define VMCNT8  asm volatile("s_waitcnt vmcnt(8)" ::: "memory");

#define RDB(d00, d01, d02, d03, d10, d11, d12, d13) \
  d00 = *(const bf16x8*)(myrep + (0 * 64 + lane) * 16); \
  d01 = *(const bf16x8*)(myrep + (1 * 64 + lane) * 16); \
  d02 = *(const bf16x8*)(myrep + (2 * 64 + lane) * 16); \
  d03 = *(const bf16x8*)(myrep + (3 * 64 + lane) * 16); \
  d10 = *(const bf16x8*)(myrep + (4 * 64 + lane) * 16); \
  d11 = *(const bf16x8*)(myrep + (5 * 64 + lane) * 16); \
  d12 = *(const bf16x8*)(myrep + (6 * 64 + lane) * 16); \
  d13 = *(const bf16x8*)(myrep + (7 * 64 + lane) * 16);

#define LOADX(d0, d1, basep, kk) { \
  float4 a0 = *(const float4*)((basep) + r0 + (kk) * 32); \
  float4 a1 = *(const float4*)((basep) + r0 + (kk) * 32 + 4); \
  float4 b0 = *(const float4*)((basep) + r1 + (kk) * 32); \
  float4 b1 = *(const float4*)((basep) + r1 + (kk) * 32 + 4); \
  d0 = cvt8(a0, a1); d1 = cvt8(b0, b1); }

#define ST(av, mt, nb) { f32x4 v = av; \
  *(float4*)(out + (rowbase + (mt) * 16 + c) * 128 + (nb) * 16 + g * 4) = \
      (float4){v[0], v[1], v[2], v[3]}; }

// LDS map: WA 0..32K | WB 32K..64K | BIAS 64K..64K+2K. 66KB -> 2 blocks/CU.
// W phases: WA={Wm1-lo, conv, Wu1-hi, conv}  WB={Wm1-hi, Wm2, Wu1-lo, Wu2}
__global__ __launch_bounds__(256) void fused_mp(
    const float* __restrict__ hself, const float* __restrict__ hother,
    const bf16_t* __restrict__ wt,
    const float* __restrict__ bm1, const float* __restrict__ bm2,
    const float* __restrict__ bu1, const float* __restrict__ bu2,
    float* __restrict__ out) {
  __shared__ char smem[67584];

  const int tid = threadIdx.x;
  const int lane = tid & 63;
  const int wave = tid >> 6;
  const int c = lane & 15;
  const int g = lane >> 4;

  char* WA = smem;
  char* WB = smem + 32768;
  char* BIAS = smem + 65536;
  char* myrep = smem + wave * 8192;  // conv region inside WA (wave-private 8KB)

  const size_t rowbase = (size_t)blockIdx.x * BM + wave * 32;
  const size_t r0 = (rowbase + c) * 128 + g * 8;
  const size_t r1 = (rowbase + 16 + c) * 128 + g * 8;

  // ---- prologue: x loads (hself), then async W DMA, then x loads (hother) ----
  bf16x8 hs00, hs01, hs02, hs03, hs10, hs11, hs12, hs13;
  bf16x8 ho00, ho01, ho02, ho03, ho10, ho11, ho12, ho13;
  LOADX(hs00, hs10, hself, 0)
  LOADX(hs01, hs11, hself, 1)
  LOADX(hs02, hs12, hself, 2)
  LOADX(hs03, hs13, hself, 3)
  STAGE32(WA, 0)      // Wm1 ks0-3
  STAGE32(WB, 2048)   // Wm1 ks4-7
  if (wave == 0 && lane < 32) {
    gload_lds16((const char*)bm1 + lane * 16, BIAS);
    gload_lds16((const char*)bm2 + lane * 16, BIAS + 512);
    gload_lds16((const char*)bu1 + lane * 16, BIAS + 1024);
    gload_lds16((const char*)bu2 + lane * 16, BIAS + 1536);
  }
  LOADX(ho00, ho10, hother, 0)
  LOADX(ho01, ho11, hother, 1)
  LOADX(ho02, ho12, hother, 2)
  LOADX(ho03, ho13, hother, 3)
  VMCNT0
  __syncthreads();  // B0: Wm1 + biases staged

  f32x4 acc00, acc01, acc02, acc03, acc04, acc05, acc06, acc07;
  f32x4 acc10, acc11, acc12, acc13, acc14, acc15, acc16, acc17;
  bf16x8 wa0, wa1, wa2, wa3, wa4, wa5, wa6, wa7;
  bf16x8 wb0, wb1, wb2, wb3, wb4, wb5, wb6, wb7;

  // ============ GEMM1: h1^T = Wm1^T [hs|ho]^T  (+bm1, relu) ============
  ACCINIT_L(0)
  LDW8(wa, WA, 0)
  LDW8(wb, WA, 8)   ROUND(wa, hs00, hs10)
  LDW8(wa, WA, 16)  ROUND(wb, hs01, hs11)
  LDW8(wb, WA, 24)  ROUND(wa, hs02, hs12)
  LDW8(wa, WB, 0)   ROUND(wb, hs03, hs13)
  LDW8(wb, WB, 8)   ROUND(wa, ho00, ho10)
  LDW8(wa, WB, 16)  ROUND(wb, ho01, ho11)
  LDW8(wb, WB, 24)  ROUND(wa, ho02, ho12)
                    ROUND(wb, ho03, ho13)
  __syncthreads();  // B1: all GEMM1 reads done

  STAGE32(WB, 4096)  // Wm2 -> WB (async, overlaps repack)
  RPK_ALL(true)      // conv -> WA (wave-private)
  WAITLDS
  bf16x8 t00, t01, t02, t03, t10, t11, t12, t13;
  RDB(t00, t01, t02, t03, t10, t11, t12, t13)
  VMCNT0
  __syncthreads();  // B2: Wm2 staged everywhere

  // ============ GEMM2: msg^T = Wm2^T h1^T  (+bm2) ============
  ACCINIT_L(512)
  LDW8(wa, WB, 0)
  LDW8(wb, WB, 8)   ROUND(wa, t00, t10)
  LDW8(wa, WB, 16)  ROUND(wb, t01, t11)
  LDW8(wb, WB, 24)  ROUND(wa, t02, t12)
                    ROUND(wb, t03, t13)
  __syncthreads();  // B3: GEMM2 reads done

  STAGE32(WB, 6144)  // Wu1 ks0-3 (hs part) -> WB
  RPK_ALL(false)     // msg conv -> WA
  WAITLDS
  bf16x8 m00, m01, m02, m03, m10, m11, m12, m13;
  RDB(m00, m01, m02, m03, m10, m11, m12, m13)
  __syncthreads();  // B4: conv consumed by all waves; WA free

  STAGE32(WA, 8192)  // Wu1 ks4-7 (msg part) -> WA
  VMCNT8             // oldest 8 (Wu1-lo) landed; Wu1-hi still in flight
  __syncthreads();  // B5: Wu1-lo staged everywhere

  // ============ GEMM3: h2^T = Wu1^T [hs|msg]^T  (+bu1, relu) ============
  ACCINIT_L(1024)
  LDW8(wa, WB, 0)
  LDW8(wb, WB, 8)   ROUND(wa, hs00, hs10)
  LDW8(wa, WB, 16)  ROUND(wb, hs01, hs11)
  LDW8(wb, WB, 24)  ROUND(wa, hs02, hs12)
                    ROUND(wb, hs03, hs13)
  VMCNT0
  __syncthreads();  // B6: Wu1-hi staged everywhere
  LDW8(wa, WA, 0)
  LDW8(wb, WA, 8)   ROUND(wa, m00, m10)
  LDW8(wa, WA, 16)  ROUND(wb, m01, m11)
  LDW8(wb, WA, 24)  ROUND(wa, m02, m12)
                    ROUND(wb, m03, m13)
  __syncthreads();  // B7: GEMM3 reads done

  STAGE32(WB, 10240)  // Wu2 -> WB
  RPK_ALL(true)       // h2 conv -> WA
  WAITLDS
  RDB(t00, t01, t02, t03, t10, t11, t12, t13)
  VMCNT0
  __syncthreads();  // B8: Wu2 staged everywhere

  // ============ GEMM4: out^T = Wu2^T h2^T  (+bu2) ============
  ACCINIT_L(1536)
  LDW8(wa, WB, 0)
  LDW8(wb, WB, 8)   ROUND(wa, t00, t10)
  LDW8(wa, WB, 16)  ROUND(wb, t01, t11)
  LDW8(wb, WB, 24)  ROUND(wa, t02, t12)
                    ROUND(wb, t03, t13)

  ST(acc00, 0, 0) ST(acc01, 0, 1) ST(acc02, 0, 2) ST(acc03, 0, 3)
  ST(acc04, 0, 4) ST(acc05, 0, 5) ST(acc06, 0, 6) ST(acc07, 0, 7)
  ST(acc10, 1, 0) ST(acc11, 1, 1) ST(acc12, 1, 2) ST(acc13, 1, 3)
  ST(acc14, 1, 4) ST(acc15, 1, 5) ST(acc16, 1, 6) ST(acc17, 1, 7)
}

extern "C" void kernel_launch(void* const* d_in, const int* in_sizes, int n_in,
                              void* d_out, int out_size, void* d_ws, size_t ws_size,
                              hipStream_t stream) {
  const float* hself  = (const float*)d_in[0];
  const float* hother = (const float*)d_in[1];
  const float* Wm1 = (const float*)d_in[2];
  const float* bm1 = (const float*)d_in[3];
  const float* Wm2 = (const float*)d_in[4];
  const float* bm2 = (const float*)d_in[5];
  const float* Wu1 = (const float*)d_in[6];
  const float* bu1 = (const float*)d_in[7];
  const float* Wu2 = (const float*)d_in[8];
  const float* bu2 = (const float*)d_in[9];
  float* out = (float*)d_out;
  bf16_t* wt = (bf16_t*)d_ws;  // 196608 B of fragment-ordered bf16 weights

  prep_weights<<<48, 256, 0, stream>>>(Wm1, Wm2, Wu1, Wu2, wt);
  fused_mp<<<E_ROWS / BM, 256, 0, stream>>>(hself, hother, wt,
                                            bm1, bm2, bu1, bu2, out);
}